// Round 2
// baseline (35192.612 us; speedup 1.0000x reference)
//
#include <hip/hip_runtime.h>
#include <cstdint>
#include <cstddef>

#define T_STEPS 1024
#define BATCH   128
#define INF     128   // used input features (130 minus last 2)
#define HID     512
#define G4      2048  // 4*HID
#define KTOT    640   // 128 x-k + 512 h-k
#define NBLK    256
#define NTHR    512
#define WLDS_FLOATS (KTOT * 32)          // 20480 floats = 80 KB
#define RED_FLOATS  (8 * 1024)           // 8 k-slices x (32g x 32b)
#define SMEM_BYTES  ((WLDS_FLOATS + RED_FLOATS) * 4)   // 114688 B

// ---------------- init / transpose kernels (run once per call) ----------------

// xT[t][i][b] = inputs[b][t][i], i < 128  (drop last 2 features)
__global__ __launch_bounds__(256) void k_transpose_x(const float* __restrict__ in,
                                                     float* __restrict__ xT)
{
  int blk = blockIdx.x;            // t*4 + bg
  int t = blk >> 2, bg = blk & 3;
  __shared__ float tile[32][129];
  int tid = threadIdx.x;
  #pragma unroll
  for (int rep = 0; rep < 16; ++rep) {
    int idx = rep * 256 + tid;
    int bl = idx >> 7, i = idx & 127;
    tile[bl][i] = in[((size_t)(bg * 32 + bl) * T_STEPS + t) * 130 + i];
  }
  __syncthreads();
  #pragma unroll
  for (int rep = 0; rep < 16; ++rep) {
    int idx = rep * 256 + tid;
    int i = idx >> 5, bl = idx & 31;
    xT[((size_t)t * INF + i) * BATCH + bg * 32 + bl] = tile[bl][i];
  }
}

// WT[k][g]: k<128 -> W_ih[g][k], else W_hh[g][k-128]
__global__ __launch_bounds__(256) void k_transpose_w(const float* __restrict__ Wih,
                                                     const float* __restrict__ Whh,
                                                     float* __restrict__ WT)
{
  int k = blockIdx.x;  // 0..639
  for (int g = threadIdx.x; g < G4; g += 256) {
    float v = (k < INF) ? Wih[(size_t)g * INF + k] : Whh[(size_t)g * HID + (k - INF)];
    WT[(size_t)k * G4 + g] = v;
  }
}

// hb0[k][b] = h0[b][k]; zero barrier counters
__global__ __launch_bounds__(256) void k_init_state(const float* __restrict__ h0,
                                                    float* __restrict__ hb0,
                                                    unsigned* __restrict__ ctr)
{
  int idx = blockIdx.x * 256 + threadIdx.x;   // 0 .. 512*128-1
  int k = idx >> 7, b = idx & 127;
  hb0[idx] = h0[(size_t)b * HID + k];
  if (idx < 64) ctr[idx] = 0;
}

// ---------------- persistent LSTM kernel ----------------
// 256 blocks = 64 unit-groups (8 units) x 4 batch-groups (32 b). 1 block/CU.
// 512 threads = 8 waves, each wave owns an 80-wide k-slice of the 640-deep GEMM.
// Lane tile: 2 gate-rows x 8 batch. W slice (80KB) persistent in LDS.
__global__ __launch_bounds__(NTHR, 2) void k_persist(
    const float* __restrict__ xT,     // [T][128][128] (t,i,b)
    const float* __restrict__ WT,     // [640][2048]   (k,g)
    const float* __restrict__ bih, const float* __restrict__ bhh,
    float* __restrict__ hb0,          // [512][128] ping
    float* __restrict__ hb1,          // [512][128] pong
    const float* __restrict__ c0,     // [128][512]
    const int* __restrict__ len,
    float* __restrict__ out,          // [128][512]
    unsigned* __restrict__ ctr)       // 4 counters, 64B apart
{
  extern __shared__ float smem[];
  float* Wlds = smem;                    // [640][32]
  float* red  = smem + WLDS_FLOATS;      // [8][32*32]

  const int blk = blockIdx.x;
  const int ug = blk & 63, bg = blk >> 6;
  const int tid = threadIdx.x;

  // ---- load W slice into LDS: Wlds[k][j], j = q*8+u -> g = q*512 + ug*8 + u
  for (int idx = tid; idx < WLDS_FLOATS; idx += NTHR) {
    int k = idx >> 5, j = idx & 31;
    int q = j >> 3, u = j & 7;
    Wlds[idx] = WT[(size_t)k * G4 + q * HID + ug * 8 + u];
  }

  // ---- per-cell registers (threads 0..255: one (b,u) cell each)
  float c_reg = 0.f, bs0 = 0.f, bs1 = 0.f, bs2 = 0.f, bs3 = 0.f;
  int mylen = -1, gb = 0, hu = 0;
  if (tid < 256) {
    int b = tid & 31, u = tid >> 5;
    gb = bg * 32 + b; hu = ug * 8 + u;
    c_reg = c0[(size_t)gb * HID + hu];
    mylen = len[gb];
    bs0 = bih[hu]           + bhh[hu];
    bs1 = bih[HID + hu]     + bhh[HID + hu];
    bs2 = bih[2 * HID + hu] + bhh[2 * HID + hu];
    bs3 = bih[3 * HID + hu] + bhh[3 * HID + hu];
  }
  __syncthreads();

  const int w  = tid >> 6, l = tid & 63;
  const int g2 = (l >> 2) * 2;        // local gate-row base (2 per lane)
  const int b0 = (l & 3) * 8;         // local batch base (8 per lane)
  const int k0 = w * 80, k1 = k0 + 80;
  const int babs = bg * 32 + b0;
  unsigned* myctr = ctr + bg * 16;

  for (int t = 0; t < T_STEPS; ++t) {
    // ---- wait for previous step's h (inter-block, per-bg barrier)
    if (t > 0) {
      if (tid == 0) {
        unsigned tgt = (unsigned)(64 * t);
        while (__hip_atomic_load(myctr, __ATOMIC_RELAXED, __HIP_MEMORY_SCOPE_AGENT) < tgt)
          __builtin_amdgcn_s_sleep(1);
        __threadfence();   // acquire: invalidate stale L1/L2 lines
      }
      __syncthreads();     // (A) also separates red reads (t-1) from red writes (t)
    }
    const float* __restrict__ hprev = (t & 1) ? hb1 : hb0;
    float*       __restrict__ hnext = (t & 1) ? hb0 : hb1;

    float acc[2][8];
    #pragma unroll
    for (int a = 0; a < 2; ++a)
      #pragma unroll
      for (int b = 0; b < 8; ++b) acc[a][b] = 0.f;

    const float* xbase = xT + (size_t)t * INF * BATCH;

    // x part of this wave's k-slice
    int kxe = (k1 < INF) ? k1 : INF;
    #pragma unroll 4
    for (int k = k0; k < kxe; ++k) {
      const float* src = xbase + (size_t)k * BATCH + babs;
      float4 ha = *(const float4*)(src);
      float4 hb = *(const float4*)(src + 4);
      float2 wv = *(const float2*)(Wlds + (k << 5) + g2);
      float hv[8] = {ha.x, ha.y, ha.z, ha.w, hb.x, hb.y, hb.z, hb.w};
      #pragma unroll
      for (int jj = 0; jj < 8; ++jj) {
        acc[0][jj] = fmaf(wv.x, hv[jj], acc[0][jj]);
        acc[1][jj] = fmaf(wv.y, hv[jj], acc[1][jj]);
      }
    }
    // h part of this wave's k-slice
    int khs = (k0 > INF) ? k0 : INF;
    #pragma unroll 4
    for (int k = khs; k < k1; ++k) {
      const float* src = hprev + (size_t)(k - INF) * BATCH + babs;
      float4 ha = *(const float4*)(src);
      float4 hb = *(const float4*)(src + 4);
      float2 wv = *(const float2*)(Wlds + (k << 5) + g2);
      float hv[8] = {ha.x, ha.y, ha.z, ha.w, hb.x, hb.y, hb.z, hb.w};
      #pragma unroll
      for (int jj = 0; jj < 8; ++jj) {
        acc[0][jj] = fmaf(wv.x, hv[jj], acc[0][jj]);
        acc[1][jj] = fmaf(wv.y, hv[jj], acc[1][jj]);
      }
    }

    // ---- write partials to LDS
    float* rp = red + w * 1024;
    #pragma unroll
    for (int gs = 0; gs < 2; ++gs) {
      *(float4*)(rp + (g2 + gs) * 32 + b0)     = make_float4(acc[gs][0], acc[gs][1], acc[gs][2], acc[gs][3]);
      *(float4*)(rp + (g2 + gs) * 32 + b0 + 4) = make_float4(acc[gs][4], acc[gs][5], acc[gs][6], acc[gs][7]);
    }
    __syncthreads();   // (B)

    // ---- cell update: threads 0..255, one (b,u) each
    if (tid < 256) {
      int b = tid & 31, u = tid >> 5;
      float s0 = bs0, s1 = bs1, s2 = bs2, s3 = bs3;
      #pragma unroll
      for (int ks = 0; ks < 8; ++ks) {
        const float* r = red + ks * 1024;
        s0 += r[(0 * 8 + u) * 32 + b];
        s1 += r[(1 * 8 + u) * 32 + b];
        s2 += r[(2 * 8 + u) * 32 + b];
        s3 += r[(3 * 8 + u) * 32 + b];
      }
      float iv = 1.f / (1.f + __expf(-s0));
      float fv = 1.f / (1.f + __expf(-s1));
      float gv = tanhf(s2);
      float ov = 1.f / (1.f + __expf(-s3));
      c_reg = fv * c_reg + iv * gv;
      float h2 = ov * tanhf(c_reg);
      hnext[(size_t)hu * BATCH + gb] = h2;
      if (t == mylen - 1) out[(size_t)gb * HID + hu] = h2;
    }
    __syncthreads();   // (C) drain h stores (vmcnt 0) before signaling
    if (tid == 0) {
      __threadfence();  // release: flush to device scope
      __hip_atomic_fetch_add(myctr, 1u, __ATOMIC_RELAXED, __HIP_MEMORY_SCOPE_AGENT);
    }
  }
}

// ---------------- launch ----------------
extern "C" void kernel_launch(void* const* d_in, const int* in_sizes, int n_in,
                              void* d_out, int out_size, void* d_ws, size_t ws_size,
                              hipStream_t stream)
{
  const float* inputs = (const float*)d_in[0];
  const int*   len    = (const int*)  d_in[1];
  const float* h0     = (const float*)d_in[2];
  const float* c0     = (const float*)d_in[3];
  const float* Wih    = (const float*)d_in[4];
  const float* Whh    = (const float*)d_in[5];
  const float* bih    = (const float*)d_in[6];
  const float* bhh    = (const float*)d_in[7];
  float* out = (float*)d_out;

  char* p = (char*)d_ws;
  float* xT = (float*)p;  p += (size_t)T_STEPS * INF * BATCH * sizeof(float);  // 64 MB
  float* WT = (float*)p;  p += (size_t)KTOT * G4 * sizeof(float);              // 5.25 MB
  float* hb0 = (float*)p; p += (size_t)HID * BATCH * sizeof(float);
  float* hb1 = (float*)p; p += (size_t)HID * BATCH * sizeof(float);
  unsigned* ctr = (unsigned*)p; p += 64 * sizeof(unsigned);

  (void)hipFuncSetAttribute((const void*)k_persist,
                            hipFuncAttributeMaxDynamicSharedMemorySize, SMEM_BYTES);

  k_transpose_x<<<T_STEPS * 4, 256, 0, stream>>>(inputs, xT);
  k_transpose_w<<<KTOT, 256, 0, stream>>>(Wih, Whh, WT);
  k_init_state<<<(HID * BATCH) / 256, 256, 0, stream>>>(h0, hb0, ctr);

  void* args[] = {(void*)&xT, (void*)&WT, (void*)&bih, (void*)&bhh,
                  (void*)&hb0, (void*)&hb1, (void*)&c0, (void*)&len,
                  (void*)&out, (void*)&ctr};
  (void)hipLaunchCooperativeKernel((void*)k_persist, dim3(NBLK), dim3(NTHR),
                                   args, SMEM_BYTES, stream);
}

// Round 3
// 11365.151 us; speedup vs baseline: 3.0965x; 3.0965x over previous
//
#include <hip/hip_runtime.h>
#include <cstdint>
#include <cstddef>

#define T_STEPS 1024
#define BATCH   128
#define INF     128   // used input features (130 minus last 2)
#define HID     512
#define G4      2048  // 4*HID
#define KTOT    640
#define NBLK    256
#define NTHR    512

#define WH_FLOATS   (HID * 32)           // 16384 floats = 64 KB (W_hh slice)
#define HS_FLOATS   (HID * 32)           // 64 KB (h stage)
#define RED_FLOATS  (4 * 1024)           // 16 KB (two-phase reduction)
#define SMEM_BYTES  ((WH_FLOATS + HS_FLOATS + RED_FLOATS) * 4)   // 147456 B

// ---------------- init / transpose kernels (run once per call) ----------------

// xT[t][i][b] = inputs[b][t][i], i < 128  (drop last 2 features)
__global__ __launch_bounds__(256) void k_transpose_x(const float* __restrict__ in,
                                                     float* __restrict__ xT)
{
  int blk = blockIdx.x;            // t*4 + bg
  int t = blk >> 2, bg = blk & 3;
  __shared__ float tile[32][129];
  int tid = threadIdx.x;
  #pragma unroll
  for (int rep = 0; rep < 16; ++rep) {
    int idx = rep * 256 + tid;
    int bl = idx >> 7, i = idx & 127;
    tile[bl][i] = in[((size_t)(bg * 32 + bl) * T_STEPS + t) * 130 + i];
  }
  __syncthreads();
  #pragma unroll
  for (int rep = 0; rep < 16; ++rep) {
    int idx = rep * 256 + tid;
    int i = idx >> 5, bl = idx & 31;
    xT[((size_t)t * INF + i) * BATCH + bg * 32 + bl] = tile[bl][i];
  }
}

// WT[k][g]: k<128 -> W_ih[g][k], else W_hh[g][k-128]
__global__ __launch_bounds__(256) void k_transpose_w(const float* __restrict__ Wih,
                                                     const float* __restrict__ Whh,
                                                     float* __restrict__ WT)
{
  int k = blockIdx.x;  // 0..639
  for (int g = threadIdx.x; g < G4; g += 256) {
    float v = (k < INF) ? Wih[(size_t)g * INF + k] : Whh[(size_t)g * HID + (k - INF)];
    WT[(size_t)k * G4 + g] = v;
  }
}

// hb0 layout: [bg][k][b32] per-bg contiguous. flags zeroed.
__global__ __launch_bounds__(256) void k_init_state(const float* __restrict__ h0,
                                                    float* __restrict__ hb0,
                                                    unsigned* __restrict__ flags)
{
  int idx = blockIdx.x * 256 + threadIdx.x;   // 0 .. 65535
  int bg = idx >> 14;
  int r = idx & 16383;
  int k = r >> 5, bl = r & 31;
  hb0[idx] = h0[(size_t)(bg * 32 + bl) * HID + k];
  if (idx < 256) flags[idx] = 0;
}

// ---------------- persistent LSTM kernel ----------------
// 256 blocks = 64 unit-groups (8 units) x 4 batch-groups (32 b). 1 block/CU.
// Sync: per-block flag words (agent-scope relaxed atomics, write-through sc1);
// h transported via agent atomics; NO fences in the loop.
__global__ __launch_bounds__(NTHR, 2) void k_persist(
    const float* __restrict__ xT,     // [T][128][128] (t,i,b)
    const float* __restrict__ WT,     // [640][2048]   (k,g)
    const float* __restrict__ bih, const float* __restrict__ bhh,
    float* __restrict__ hb0,          // [4][512][32] ping (per-bg contiguous)
    float* __restrict__ hb1,          // [4][512][32] pong
    const float* __restrict__ c0,     // [128][512]
    const int* __restrict__ len,
    float* __restrict__ out,          // [128][512]
    unsigned* __restrict__ flags)     // [4][64]
{
  extern __shared__ float smem[];
  float* Whl    = smem;                    // [512][32]  W_hh slice
  float* hstage = smem + WH_FLOATS;        // [512][32]  h_{t-1} stage
  float* red    = hstage + HS_FLOATS;      // [4][1024]

  const int blk = blockIdx.x;
  const int ug = blk & 63, bg = blk >> 6;
  const int tid = threadIdx.x;

  // ---- load W_hh slice into LDS: Whl[k][j], j=q*8+u -> g=q*512+ug*8+u
  for (int idx = tid; idx < WH_FLOATS; idx += NTHR) {
    int k = idx >> 5, j = idx & 31;
    Whl[idx] = WT[(size_t)(INF + k) * G4 + (j >> 3) * HID + ug * 8 + (j & 7)];
  }

  // ---- per-cell registers (threads 0..255: one (b,u) cell each)
  float c_reg = 0.f, bs0 = 0.f, bs1 = 0.f, bs2 = 0.f, bs3 = 0.f;
  int mylen = -1, gb = 0, hu = 0;
  if (tid < 256) {
    int b = tid & 31, u = tid >> 5;
    gb = bg * 32 + b; hu = ug * 8 + u;
    c_reg = c0[(size_t)gb * HID + hu];
    mylen = len[gb];
    bs0 = bih[hu]           + bhh[hu];
    bs1 = bih[HID + hu]     + bhh[HID + hu];
    bs2 = bih[2 * HID + hu] + bhh[2 * HID + hu];
    bs3 = bih[3 * HID + hu] + bhh[3 * HID + hu];
  }
  __syncthreads();

  const int w  = tid >> 6, l = tid & 63;
  const int g2 = (l >> 2) * 2;        // local gate-row base (2 per lane)
  const int b0 = (l & 3) * 8;         // local batch base (8 per lane)
  const int babs = bg * 32 + b0;
  const int kx0 = w * 16;             // this wave's x k-slice
  const int kh0 = w * 64;             // this wave's h k-slice
  const float* wxbase = WT + (size_t)(g2 >> 3) * HID + ug * 8 + (g2 & 7);
  unsigned* myflags = flags + bg * 64;
  float* hslab0 = hb0 + (size_t)bg * (HID * 32);
  float* hslab1 = hb1 + (size_t)bg * (HID * 32);

  for (int t = 0; t < T_STEPS; ++t) {
    // ---- wait for all 64 peer blocks of this bg to finish step t-1
    if (t) {
      if (tid < 64) {
        while (__hip_atomic_load(myflags + tid, __ATOMIC_RELAXED,
                                 __HIP_MEMORY_SCOPE_AGENT) < (unsigned)t)
          __builtin_amdgcn_s_sleep(2);
      }
      __syncthreads();
    }
    const float* hprev = (t & 1) ? hslab1 : hslab0;
    float*       hnext = (t & 1) ? hslab0 : hslab1;

    // ---- issue h stage loads (uncached, far point) — latency hidden by x-part
    unsigned long long hreg[16];
    const unsigned long long* hsrc = (const unsigned long long*)hprev;
    #pragma unroll
    for (int j = 0; j < 16; ++j)
      hreg[j] = __hip_atomic_load(hsrc + j * NTHR + tid, __ATOMIC_RELAXED,
                                  __HIP_MEMORY_SCOPE_AGENT);

    float acc[2][8];
    #pragma unroll
    for (int a = 0; a < 2; ++a)
      #pragma unroll
      for (int b = 0; b < 8; ++b) acc[a][b] = 0.f;

    // ---- x-part GEMM (global, cached; no dependency on h)
    const float* xbase = xT + (size_t)t * INF * BATCH;
    #pragma unroll 4
    for (int k = kx0; k < kx0 + 16; ++k) {
      const float* src = xbase + (size_t)k * BATCH + babs;
      float4 ha = *(const float4*)(src);
      float4 hb = *(const float4*)(src + 4);
      float2 wv = *(const float2*)(wxbase + (size_t)k * G4);
      float hv[8] = {ha.x, ha.y, ha.z, ha.w, hb.x, hb.y, hb.z, hb.w};
      #pragma unroll
      for (int jj = 0; jj < 8; ++jj) {
        acc[0][jj] = fmaf(wv.x, hv[jj], acc[0][jj]);
        acc[1][jj] = fmaf(wv.y, hv[jj], acc[1][jj]);
      }
    }

    // ---- write staged h to LDS
    unsigned long long* hst = (unsigned long long*)hstage;
    #pragma unroll
    for (int j = 0; j < 16; ++j) hst[j * NTHR + tid] = hreg[j];
    __syncthreads();

    // ---- h-part GEMM (h from LDS, W from LDS)
    #pragma unroll 4
    for (int k = kh0; k < kh0 + 64; ++k) {
      const float* src = hstage + (k << 5) + b0;
      float4 ha = *(const float4*)(src);
      float4 hb = *(const float4*)(src + 4);
      float2 wv = *(const float2*)(Whl + (k << 5) + g2);
      float hv[8] = {ha.x, ha.y, ha.z, ha.w, hb.x, hb.y, hb.z, hb.w};
      #pragma unroll
      for (int jj = 0; jj < 8; ++jj) {
        acc[0][jj] = fmaf(wv.x, hv[jj], acc[0][jj]);
        acc[1][jj] = fmaf(wv.y, hv[jj], acc[1][jj]);
      }
    }

    // ---- two-phase cross-wave reduction (waves 4-7 -> LDS, waves 0-3 add)
    if (w >= 4) {
      float* rp = red + (w - 4) * 1024;
      #pragma unroll
      for (int gs = 0; gs < 2; ++gs) {
        *(float4*)(rp + (g2 + gs) * 32 + b0)     = make_float4(acc[gs][0], acc[gs][1], acc[gs][2], acc[gs][3]);
        *(float4*)(rp + (g2 + gs) * 32 + b0 + 4) = make_float4(acc[gs][4], acc[gs][5], acc[gs][6], acc[gs][7]);
      }
    }
    __syncthreads();
    if (w < 4) {
      float* rp = red + w * 1024;
      #pragma unroll
      for (int gs = 0; gs < 2; ++gs) {
        float4 r0 = *(float4*)(rp + (g2 + gs) * 32 + b0);
        float4 r1 = *(float4*)(rp + (g2 + gs) * 32 + b0 + 4);
        *(float4*)(rp + (g2 + gs) * 32 + b0)     = make_float4(acc[gs][0] + r0.x, acc[gs][1] + r0.y, acc[gs][2] + r0.z, acc[gs][3] + r0.w);
        *(float4*)(rp + (g2 + gs) * 32 + b0 + 4) = make_float4(acc[gs][4] + r1.x, acc[gs][5] + r1.y, acc[gs][6] + r1.z, acc[gs][7] + r1.w);
      }
    }
    __syncthreads();

    // ---- cell update: threads 0..255, one (b,u) each
    if (tid < 256) {
      int b = tid & 31, u = tid >> 5;
      float s0 = bs0, s1 = bs1, s2 = bs2, s3 = bs3;
      #pragma unroll
      for (int ks = 0; ks < 4; ++ks) {
        const float* r = red + ks * 1024;
        s0 += r[(0 * 8 + u) * 32 + b];
        s1 += r[(1 * 8 + u) * 32 + b];
        s2 += r[(2 * 8 + u) * 32 + b];
        s3 += r[(3 * 8 + u) * 32 + b];
      }
      float iv = 1.f / (1.f + __expf(-s0));
      float fv = 1.f / (1.f + __expf(-s1));
      float gv = tanhf(s2);
      float ov = 1.f / (1.f + __expf(-s3));
      c_reg = fv * c_reg + iv * gv;
      float h2 = ov * tanhf(c_reg);
      __hip_atomic_store(&hnext[hu * 32 + b], h2, __ATOMIC_RELAXED,
                         __HIP_MEMORY_SCOPE_AGENT);
      if (t == mylen - 1) out[(size_t)gb * HID + hu] = h2;
    }
    __syncthreads();   // drains all waves' vmcnt before flag store
    if (tid == 0)
      __hip_atomic_store(myflags + ug, (unsigned)(t + 1), __ATOMIC_RELAXED,
                         __HIP_MEMORY_SCOPE_AGENT);
  }
}

// ---------------- launch ----------------
extern "C" void kernel_launch(void* const* d_in, const int* in_sizes, int n_in,
                              void* d_out, int out_size, void* d_ws, size_t ws_size,
                              hipStream_t stream)
{
  const float* inputs = (const float*)d_in[0];
  const int*   len    = (const int*)  d_in[1];
  const float* h0     = (const float*)d_in[2];
  const float* c0     = (const float*)d_in[3];
  const float* Wih    = (const float*)d_in[4];
  const float* Whh    = (const float*)d_in[5];
  const float* bih    = (const float*)d_in[6];
  const float* bhh    = (const float*)d_in[7];
  float* out = (float*)d_out;

  char* p = (char*)d_ws;
  float* xT = (float*)p;  p += (size_t)T_STEPS * INF * BATCH * sizeof(float);  // 64 MB
  float* WT = (float*)p;  p += (size_t)KTOT * G4 * sizeof(float);              // 5.25 MB
  float* hb0 = (float*)p; p += (size_t)HID * BATCH * sizeof(float);
  float* hb1 = (float*)p; p += (size_t)HID * BATCH * sizeof(float);
  unsigned* flags = (unsigned*)p; p += 256 * sizeof(unsigned);

  (void)hipFuncSetAttribute((const void*)k_persist,
                            hipFuncAttributeMaxDynamicSharedMemorySize, SMEM_BYTES);

  k_transpose_x<<<T_STEPS * 4, 256, 0, stream>>>(inputs, xT);
  k_transpose_w<<<KTOT, 256, 0, stream>>>(Wih, Whh, WT);
  k_init_state<<<(HID * BATCH) / 256, 256, 0, stream>>>(h0, hb0, flags);

  void* args[] = {(void*)&xT, (void*)&WT, (void*)&bih, (void*)&bhh,
                  (void*)&hb0, (void*)&hb1, (void*)&c0, (void*)&len,
                  (void*)&out, (void*)&flags};
  (void)hipLaunchCooperativeKernel((void*)k_persist, dim3(NBLK), dim3(NTHR),
                                   args, SMEM_BYTES, stream);
}

// Round 4
// 5265.513 us; speedup vs baseline: 6.6836x; 2.1584x over previous
//
#include <hip/hip_runtime.h>
#include <hip/hip_bf16.h>
#include <cstdint>
#include <cstddef>

#define T_STEPS 1024
#define BATCH   128
#define INF     128   // used input features (130 minus last 2)
#define HID     512
#define NBLK    128   // 32 ug x 4 bg
#define NTHR    512   // 8 waves: kq = w&3 (k quarter), bt = w>>2 (b half)
#define PK      648   // padded k stride (bf16 units) in LDS Z planes
#define Z_SHORTS    (2 * 32 * PK)            // 41472 shorts = 82944 B
#define GATE_STRIDE 34
#define GATE_FLOATS (4 * 64 * GATE_STRIDE)   // 34816 B
#define SMEM_BYTES  (Z_SHORTS * 2 + GATE_FLOATS * 4)   // 117760 B

typedef short  bf16x8 __attribute__((ext_vector_type(8)));
typedef float  f32x4  __attribute__((ext_vector_type(4)));

static __device__ __forceinline__ unsigned short bf_hi(float v) {
  __hip_bfloat16 h = __float2bfloat16(v);
  return *reinterpret_cast<unsigned short*>(&h);
}
static __device__ __forceinline__ float bf_val(unsigned short u) {
  __hip_bfloat16 h = *reinterpret_cast<__hip_bfloat16*>(&u);
  return __bfloat162float(h);
}

// ---------------- pre-pass kernels ----------------

// xp[t*4+bg][p][c 32][k 128] bf16 (p=0 hi, p=1 lo): xp[..] = split(inputs[b][t][i])
__global__ __launch_bounds__(256) void k_prep_x(const float* __restrict__ in,
                                                unsigned short* __restrict__ xp)
{
  int t = blockIdx.x >> 2, bg = blockIdx.x & 3;
  int tid = threadIdx.x;
  size_t base = (size_t)blockIdx.x * 8192;
  #pragma unroll
  for (int rep = 0; rep < 16; ++rep) {
    int idx = rep * 256 + tid;
    int c = idx >> 7, k = idx & 127;
    float v = in[((size_t)(bg * 32 + c) * T_STEPS + t) * 130 + k];
    unsigned short hi = bf_hi(v);
    unsigned short lo = bf_hi(v - bf_val(hi));
    xp[base + c * 128 + k]        = hi;
    xp[base + 4096 + c * 128 + k] = lo;
  }
}

// W A-fragments, bf16 hi/lo, in per-lane MFMA layout.
// blk = ((ug*4+tg)*4+kq)*5+s  (2560 blocks x 64 threads)
// A-frag lane mapping (16x16x32): row m = l&15, k = (l>>4)*8 + j
__global__ __launch_bounds__(64) void k_prep_w(const float* __restrict__ Wih,
                                               const float* __restrict__ Whh,
                                               unsigned short* __restrict__ wf)
{
  int blk = blockIdx.x;
  int s = blk % 5; int r = blk / 5;
  int kq = r & 3; int tg = (r >> 2) & 3; int ug = r >> 4;
  int l = threadIdx.x;
  int Grow = tg * HID + ug * 16 + (l & 15);
  int kb = kq * 160 + s * 32 + (l >> 4) * 8;
  float v[8];
  #pragma unroll
  for (int j = 0; j < 8; ++j)
    v[j] = (kb < INF) ? Wih[(size_t)Grow * INF + kb + j]
                      : Whh[(size_t)Grow * HID + (kb - INF) + j];
  unsigned short hi[8], lo[8];
  #pragma unroll
  for (int j = 0; j < 8; ++j) {
    hi[j] = bf_hi(v[j]);
    lo[j] = bf_hi(v[j] - bf_val(hi[j]));
  }
  unsigned short* dh = wf + ((size_t)(blk * 2 + 0) * 64 + l) * 8;
  unsigned short* dl = wf + ((size_t)(blk * 2 + 1) * 64 + l) * 8;
  #pragma unroll
  for (int j = 0; j < 8; ++j) { dh[j] = hi[j]; dl[j] = lo[j]; }
}

// hp0[bg][c 32][k 512] u32 = (lo<<16)|hi of h0[b][k]; zero flags
__global__ __launch_bounds__(256) void k_prep_h(const float* __restrict__ h0,
                                                unsigned* __restrict__ hp0,
                                                unsigned* __restrict__ flags)
{
  int idx = blockIdx.x * 256 + threadIdx.x;   // 0..65535
  int k = idx & 511, c = (idx >> 9) & 31, bg = idx >> 14;
  float v = h0[(size_t)(bg * 32 + c) * HID + k];
  unsigned short hi = bf_hi(v);
  unsigned short lo = bf_hi(v - bf_val(hi));
  hp0[idx] = (unsigned)hi | ((unsigned)lo << 16);
  if (blockIdx.x == 0 && threadIdx.x < 128) flags[threadIdx.x] = 0;
}

// ---------------- persistent MFMA LSTM ----------------
// 128 blocks = 32 ug (64 gate-rows = 16 units x 4 gates) x 4 bg (32 b).
// 8 waves: (kq = w&3) 160-deep k quarter, (bt = w>>2) 16-wide b half.
// Each wave: 4 g-tiles x 5 ksteps x 3 split-MFMAs, W frags in VGPRs.
__global__ __launch_bounds__(NTHR, 2) void k_persist(
    const unsigned short* __restrict__ xp,   // [t*4+bg][2][32][128]
    const unsigned short* __restrict__ wf,   // A-fragments
    const float* __restrict__ bih, const float* __restrict__ bhh,
    unsigned* __restrict__ hp0,              // [4][32][512] packed hi|lo<<16
    unsigned* __restrict__ hp1,
    const float* __restrict__ c0,            // [128][512]
    const int* __restrict__ len,
    float* __restrict__ out,                 // [128][512]
    unsigned* __restrict__ flags)            // [4][32]
{
  extern __shared__ char smem[];
  short* zpl  = (short*)smem;                      // [2][32][PK] bf16
  float* gates = (float*)(smem + Z_SHORTS * 2);    // [4 kq][64 r][34]

  const int blk = blockIdx.x;
  const int ug = blk & 31, bg = blk >> 5;
  const int tid = threadIdx.x;
  const int w = tid >> 6, l = tid & 63;
  const int kq = w & 3, bt = w >> 2;
  const int n = l & 15, gch = l >> 4;
  const int cB = bt * 16 + n;

  // ---- load W A-fragments into registers (once)
  bf16x8 A[4][5][2];
  {
    const uint4* wfq = (const uint4*)wf;
    #pragma unroll
    for (int tg = 0; tg < 4; ++tg)
      #pragma unroll
      for (int s = 0; s < 5; ++s)
        #pragma unroll
        for (int p = 0; p < 2; ++p) {
          uint4 q = wfq[(size_t)((ug * 160 + ((tg * 4 + kq) * 5 + s) * 2 + p)) * 64 + l];
          A[tg][s][p] = *reinterpret_cast<bf16x8*>(&q);
        }
  }

  // ---- per-cell state (all 512 threads: cell (cb, cu))
  const int cb = tid & 31, cu = tid >> 5;          // batch 0..31, unit 0..15
  const int gb = bg * 32 + cb, hu = ug * 16 + cu;
  float c_reg = c0[(size_t)gb * HID + hu];
  const int mylen = len[gb];
  float bsq[4];
  #pragma unroll
  for (int q = 0; q < 4; ++q) bsq[q] = bih[q * HID + hu] + bhh[q * HID + hu];

  unsigned* myflags = flags + bg * 32;

  for (int t = 0; t < T_STEPS; ++t) {
    // ---- wait for the 32 peer blocks of this bg to finish step t-1
    if (t) {
      if (tid < 32) {
        while (__hip_atomic_load(myflags + tid, __ATOMIC_RELAXED,
                                 __HIP_MEMORY_SCOPE_AGENT) < (unsigned)t)
          __builtin_amdgcn_s_sleep(1);
      }
      __syncthreads();
    }
    const unsigned* hsrc = ((t & 1) ? hp1 : hp0) + (size_t)bg * 16384;
    unsigned*       hdst = ((t & 1) ? hp0 : hp1) + (size_t)bg * 16384;

    // ---- issue h loads (far point), hide under x staging
    unsigned long long hch[16];
    const unsigned long long* hq = (const unsigned long long*)hsrc;
    #pragma unroll
    for (int j = 0; j < 16; ++j)
      hch[j] = __hip_atomic_load(hq + j * 512 + tid, __ATOMIC_RELAXED,
                                 __HIP_MEMORY_SCOPE_AGENT);

    // ---- x stage: straight copy of 16KB into LDS planes (k<128 region)
    {
      const uint4* xps = (const uint4*)(xp + (size_t)(t * 4 + bg) * 8192);
      uint4 xa = xps[tid], xb = xps[tid + 512];
      int i0 = tid;
      *(uint4*)(zpl + ((i0 >> 9) * 32 + ((i0 & 511) >> 4)) * PK + (i0 & 15) * 8) = xa;
      int i1 = tid + 512;
      *(uint4*)(zpl + ((i1 >> 9) * 32 + ((i1 & 511) >> 4)) * PK + (i1 & 15) * 8) = xb;
    }

    // ---- h stage: unpack hi/lo pairs into planes (k>=128 region)
    #pragma unroll
    for (int j = 0; j < 16; ++j) {
      int ci = j * 512 + tid;
      int c = ci >> 8, kk = (ci & 255) * 2;
      unsigned w0 = (unsigned)hch[j], w1 = (unsigned)(hch[j] >> 32);
      unsigned hipair = (w0 & 0xFFFFu) | (w1 << 16);
      unsigned lopair = (w0 >> 16) | (w1 & 0xFFFF0000u);
      *(unsigned*)(zpl + c * PK + 128 + kk)        = hipair;
      *(unsigned*)(zpl + (32 + c) * PK + 128 + kk) = lopair;
    }
    __syncthreads();

    // ---- MFMA phase: 4 g-tiles, 5 ksteps, 3 split products
    f32x4 acc[4] = {f32x4{0,0,0,0}, f32x4{0,0,0,0}, f32x4{0,0,0,0}, f32x4{0,0,0,0}};
    #pragma unroll
    for (int s = 0; s < 5; ++s) {
      int ka = kq * 160 + s * 32 + gch * 8;
      bf16x8 Bh = *(const bf16x8*)(zpl + cB * PK + ka);
      bf16x8 Bl = *(const bf16x8*)(zpl + (32 + cB) * PK + ka);
      #pragma unroll
      for (int tg = 0; tg < 4; ++tg) {
        acc[tg] = __builtin_amdgcn_mfma_f32_16x16x32_bf16(A[tg][s][0], Bh, acc[tg], 0, 0, 0);
        acc[tg] = __builtin_amdgcn_mfma_f32_16x16x32_bf16(A[tg][s][0], Bl, acc[tg], 0, 0, 0);
        acc[tg] = __builtin_amdgcn_mfma_f32_16x16x32_bf16(A[tg][s][1], Bh, acc[tg], 0, 0, 0);
      }
    }

    // ---- dump partial gates: C layout col=l&15, row=(l>>4)*4+reg
    #pragma unroll
    for (int tg = 0; tg < 4; ++tg)
      #pragma unroll
      for (int r = 0; r < 4; ++r)
        gates[(kq * 64 + tg * 16 + gch * 4 + r) * GATE_STRIDE + cB] = acc[tg][r];
    __syncthreads();

    // ---- cell update (one (cb,cu) per thread)
    float s4[4];
    #pragma unroll
    for (int q = 0; q < 4; ++q) {
      float s = bsq[q];
      #pragma unroll
      for (int kp = 0; kp < 4; ++kp)
        s += gates[(kp * 64 + q * 16 + cu) * GATE_STRIDE + cb];
      s4[q] = s;
    }
    float iv = 1.f / (1.f + __expf(-s4[0]));
    float fv = 1.f / (1.f + __expf(-s4[1]));
    float gv = tanhf(s4[2]);
    float ov = 1.f / (1.f + __expf(-s4[3]));
    c_reg = fv * c_reg + iv * gv;
    float h2 = ov * tanhf(c_reg);
    unsigned short hh = bf_hi(h2);
    unsigned short ll = bf_hi(h2 - bf_val(hh));
    __hip_atomic_store(hdst + (size_t)cb * 512 + hu,
                       (unsigned)hh | ((unsigned)ll << 16),
                       __ATOMIC_RELAXED, __HIP_MEMORY_SCOPE_AGENT);
    if (t == mylen - 1) out[(size_t)gb * HID + hu] = h2;

    __syncthreads();   // drains h stores (vmcnt 0) before flag store
    if (tid == 0)
      __hip_atomic_store(myflags + ug, (unsigned)(t + 1),
                         __ATOMIC_RELAXED, __HIP_MEMORY_SCOPE_AGENT);
  }
}

// ---------------- launch ----------------
extern "C" void kernel_launch(void* const* d_in, const int* in_sizes, int n_in,
                              void* d_out, int out_size, void* d_ws, size_t ws_size,
                              hipStream_t stream)
{
  const float* inputs = (const float*)d_in[0];
  const int*   len    = (const int*)  d_in[1];
  const float* h0     = (const float*)d_in[2];
  const float* c0     = (const float*)d_in[3];
  const float* Wih    = (const float*)d_in[4];
  const float* Whh    = (const float*)d_in[5];
  const float* bih    = (const float*)d_in[6];
  const float* bhh    = (const float*)d_in[7];
  float* out = (float*)d_out;

  char* p = (char*)d_ws;
  unsigned short* xp = (unsigned short*)p; p += (size_t)T_STEPS * 4 * 8192 * 2;      // 64 MB
  unsigned short* wf = (unsigned short*)p; p += (size_t)2560 * 2 * 64 * 8 * 2;       // 5 MB
  unsigned* hp0 = (unsigned*)p;  p += (size_t)4 * 32 * 512 * 4;                      // 256 KB
  unsigned* hp1 = (unsigned*)p;  p += (size_t)4 * 32 * 512 * 4;                      // 256 KB
  unsigned* flags = (unsigned*)p; p += 128 * 4;

  (void)hipFuncSetAttribute((const void*)k_persist,
                            hipFuncAttributeMaxDynamicSharedMemorySize, SMEM_BYTES);

  k_prep_x<<<T_STEPS * 4, 256, 0, stream>>>(inputs, xp);
  k_prep_w<<<2560, 64, 0, stream>>>(Wih, Whh, wf);
  k_prep_h<<<256, 256, 0, stream>>>(h0, hp0, flags);

  void* args[] = {(void*)&xp, (void*)&wf, (void*)&bih, (void*)&bhh,
                  (void*)&hp0, (void*)&hp1, (void*)&c0, (void*)&len,
                  (void*)&out, (void*)&flags};
  (void)hipLaunchCooperativeKernel((void*)k_persist, dim3(NBLK), dim3(NTHR),
                                   args, SMEM_BYTES, stream);
}

// Round 5
// 3755.289 us; speedup vs baseline: 9.3715x; 1.4022x over previous
//
#include <hip/hip_runtime.h>
#include <hip/hip_bf16.h>
#include <cstdint>
#include <cstddef>

#define T_STEPS 1024
#define BATCH   128
#define INF     128   // used input features (130 minus last 2)
#define HID     512
#define NBLK    256   // 64 ug x 4 bg
#define NTHR    512   // 8 waves: kq = w&3 (k quarter), bt = w>>2 (b half)
#define PK      648   // padded k stride (bf16 units) in LDS Z planes
#define Z_SHORTS    (2 * 32 * PK)            // 41472 shorts = 82944 B
#define GATE_STRIDE 34
#define GATE_FLOATS (4 * 32 * GATE_STRIDE)   // 4352 floats = 17408 B
#define SMEM_BYTES  (Z_SHORTS * 2 + GATE_FLOATS * 4)   // 100352 B

typedef short  bf16x8 __attribute__((ext_vector_type(8)));
typedef float  f32x4  __attribute__((ext_vector_type(4)));

static __device__ __forceinline__ unsigned short bf_hi(float v) {
  __hip_bfloat16 h = __float2bfloat16(v);
  return *reinterpret_cast<unsigned short*>(&h);
}
static __device__ __forceinline__ float bf_val(unsigned short u) {
  __hip_bfloat16 h = *reinterpret_cast<__hip_bfloat16*>(&u);
  return __bfloat162float(h);
}

// ---------------- pre-pass kernels ----------------

// xp[t*4+bg][p][c 32][k 128] bf16 (p=0 hi, p=1 lo)
__global__ __launch_bounds__(256) void k_prep_x(const float* __restrict__ in,
                                                unsigned short* __restrict__ xp)
{
  int t = blockIdx.x >> 2, bg = blockIdx.x & 3;
  int tid = threadIdx.x;
  size_t base = (size_t)blockIdx.x * 8192;
  #pragma unroll
  for (int rep = 0; rep < 16; ++rep) {
    int idx = rep * 256 + tid;
    int c = idx >> 7, k = idx & 127;
    float v = in[((size_t)(bg * 32 + c) * T_STEPS + t) * 130 + k];
    unsigned short hi = bf_hi(v);
    unsigned short lo = bf_hi(v - bf_val(hi));
    xp[base + c * 128 + k]        = hi;
    xp[base + 4096 + c * 128 + k] = lo;
  }
}

// W A-fragments, bf16 hi/lo, per-lane MFMA layout.
// blk = ((ug*2+tg)*4+kq)*5+s   (2560 blocks x 64 threads)
// tile tg covers gates {2tg,2tg+1} x 8 units: local row r -> q=2tg+(r>>3), u=r&7
// A-frag lane mapping (16x16x32): row = l&15, k = (l>>4)*8 + j
__global__ __launch_bounds__(64) void k_prep_w(const float* __restrict__ Wih,
                                               const float* __restrict__ Whh,
                                               unsigned short* __restrict__ wf)
{
  int blk = blockIdx.x;
  int s = blk % 5; int r = blk / 5;
  int kq = r & 3; int tg = (r >> 2) & 1; int ug = r >> 3;
  int l = threadIdx.x;
  int q = tg * 2 + ((l & 15) >> 3);
  int Grow = q * HID + ug * 8 + (l & 7);
  int kb = kq * 160 + s * 32 + (l >> 4) * 8;
  float v[8];
  #pragma unroll
  for (int j = 0; j < 8; ++j)
    v[j] = (kb < INF) ? Wih[(size_t)Grow * INF + kb + j]
                      : Whh[(size_t)Grow * HID + (kb - INF) + j];
  unsigned short hi[8], lo[8];
  #pragma unroll
  for (int j = 0; j < 8; ++j) {
    hi[j] = bf_hi(v[j]);
    lo[j] = bf_hi(v[j] - bf_val(hi[j]));
  }
  unsigned short* dh = wf + ((size_t)(blk * 2 + 0) * 64 + l) * 8;
  unsigned short* dl = wf + ((size_t)(blk * 2 + 1) * 64 + l) * 8;
  #pragma unroll
  for (int j = 0; j < 8; ++j) { dh[j] = hi[j]; dl[j] = lo[j]; }
}

// hp0[bg][c 32][k 512] u32 = hi | lo<<16 of h0[b][k]; zero flags (256)
__global__ __launch_bounds__(256) void k_prep_h(const float* __restrict__ h0,
                                                unsigned* __restrict__ hp0,
                                                unsigned* __restrict__ flags)
{
  int idx = blockIdx.x * 256 + threadIdx.x;   // 0..65535
  int k = idx & 511, c = (idx >> 9) & 31, bg = idx >> 14;
  float v = h0[(size_t)(bg * 32 + c) * HID + k];
  unsigned short hi = bf_hi(v);
  unsigned short lo = bf_hi(v - bf_val(hi));
  hp0[idx] = (unsigned)hi | ((unsigned)lo << 16);
  if (blockIdx.x == 0 && threadIdx.x < 256) flags[threadIdx.x] = 0;
}

// ---------------- persistent MFMA LSTM ----------------
// 256 blocks = 64 ug (8 units = 32 gate-rows) x 4 bg (32 b). 1 block/CU.
// 8 waves: kq = w&3 (160-deep k quarter), bt = w>>2 (16-wide b half).
// Per wave: 2 row-tiles x 5 ksteps x 3 split-MFMAs; 20 A-frags in VGPRs.
__global__ __launch_bounds__(NTHR, 2) void k_persist(
    const unsigned short* __restrict__ xp,   // [t*4+bg][2][32][128]
    const unsigned short* __restrict__ wf,   // A-fragments
    const float* __restrict__ bih, const float* __restrict__ bhh,
    unsigned* __restrict__ hp0,              // [4][32][512] packed hi|lo<<16
    unsigned* __restrict__ hp1,
    const float* __restrict__ c0,            // [128][512]
    const int* __restrict__ len,
    float* __restrict__ out,                 // [128][512]
    unsigned* __restrict__ flags)            // [4][64]
{
  extern __shared__ char smem[];
  short* zpl  = (short*)smem;                      // [2][32][PK] bf16
  float* gates = (float*)(smem + Z_SHORTS * 2);    // [4 kq][32 r][34]

  const int blk = blockIdx.x;
  const int ug = blk & 63, bg = blk >> 6;
  const int tid = threadIdx.x;
  const int w = tid >> 6, l = tid & 63;
  const int kq = w & 3, bt = w >> 2;
  const int n = l & 15, gch = l >> 4;
  const int cB = bt * 16 + n;

  // ---- load W A-fragments into registers (once): 20 frags = 80 VGPR
  bf16x8 A[2][5][2];
  {
    const uint4* wfq = (const uint4*)wf;
    #pragma unroll
    for (int tg = 0; tg < 2; ++tg)
      #pragma unroll
      for (int s = 0; s < 5; ++s)
        #pragma unroll
        for (int p = 0; p < 2; ++p) {
          uint4 q = wfq[(size_t)(ug * 80 + ((tg * 4 + kq) * 5 + s) * 2 + p) * 64 + l];
          A[tg][s][p] = *reinterpret_cast<bf16x8*>(&q);
        }
  }

  // ---- per-cell state (threads 0..255: cell (cb, cu), cu 0..7)
  const int cb = tid & 31, cu = (tid >> 5) & 7;
  const int gb = bg * 32 + cb, hu = ug * 8 + cu;
  float c_reg = 0.f, bsq[4] = {0.f, 0.f, 0.f, 0.f};
  int mylen = -1;
  if (tid < 256) {
    c_reg = c0[(size_t)gb * HID + hu];
    mylen = len[gb];
    #pragma unroll
    for (int q = 0; q < 4; ++q) bsq[q] = bih[q * HID + hu] + bhh[q * HID + hu];
  }

  unsigned* myflags = flags + bg * 64;

  for (int t = 0; t < T_STEPS; ++t) {
    // ---- x stage (h-independent): straight 16KB copy into LDS planes (k<128)
    // prior iteration's final __syncthreads guarantees zpl is free.
    {
      const uint4* xps = (const uint4*)(xp + (size_t)(t * 4 + bg) * 8192);
      uint4 xa = xps[tid], xb = xps[tid + 512];
      int i0 = tid;
      *(uint4*)(zpl + ((i0 >> 9) * 32 + ((i0 & 511) >> 4)) * PK + (i0 & 15) * 8) = xa;
      int i1 = tid + 512;
      *(uint4*)(zpl + ((i1 >> 9) * 32 + ((i1 & 511) >> 4)) * PK + (i1 & 15) * 8) = xb;
    }

    // ---- wait for the 64 peer blocks of this bg to finish step t-1
    if (t) {
      if (tid < 64) {
        while (__hip_atomic_load(myflags + tid, __ATOMIC_RELAXED,
                                 __HIP_MEMORY_SCOPE_AGENT) < (unsigned)t)
          __builtin_amdgcn_s_sleep(1);
      }
      __syncthreads();
    }
    const unsigned* hsrc = ((t & 1) ? hp1 : hp0) + (size_t)bg * 16384;
    unsigned*       hdst = ((t & 1) ? hp0 : hp1) + (size_t)bg * 16384;

    // ---- h load (far point) + stage into planes (k>=128)
    unsigned long long hch[16];
    const unsigned long long* hq = (const unsigned long long*)hsrc;
    #pragma unroll
    for (int j = 0; j < 16; ++j)
      hch[j] = __hip_atomic_load(hq + j * 512 + tid, __ATOMIC_RELAXED,
                                 __HIP_MEMORY_SCOPE_AGENT);
    #pragma unroll
    for (int j = 0; j < 16; ++j) {
      int ci = j * 512 + tid;
      int c = ci >> 8, kk = (ci & 255) * 2;
      unsigned w0 = (unsigned)hch[j], w1 = (unsigned)(hch[j] >> 32);
      unsigned hipair = (w0 & 0xFFFFu) | (w1 << 16);
      unsigned lopair = (w0 >> 16) | (w1 & 0xFFFF0000u);
      *(unsigned*)(zpl + c * PK + 128 + kk)        = hipair;
      *(unsigned*)(zpl + (32 + c) * PK + 128 + kk) = lopair;
    }
    __syncthreads();

    // ---- MFMA phase: 2 row-tiles, 5 ksteps, 3 split products
    f32x4 acc[2] = {f32x4{0,0,0,0}, f32x4{0,0,0,0}};
    #pragma unroll
    for (int s = 0; s < 5; ++s) {
      int ka = kq * 160 + s * 32 + gch * 8;
      bf16x8 Bh = *(const bf16x8*)(zpl + cB * PK + ka);
      bf16x8 Bl = *(const bf16x8*)(zpl + (32 + cB) * PK + ka);
      #pragma unroll
      for (int tg = 0; tg < 2; ++tg) {
        acc[tg] = __builtin_amdgcn_mfma_f32_16x16x32_bf16(A[tg][s][0], Bh, acc[tg], 0, 0, 0);
        acc[tg] = __builtin_amdgcn_mfma_f32_16x16x32_bf16(A[tg][s][0], Bl, acc[tg], 0, 0, 0);
        acc[tg] = __builtin_amdgcn_mfma_f32_16x16x32_bf16(A[tg][s][1], Bh, acc[tg], 0, 0, 0);
      }
    }

    // ---- dump partial gates: C layout col=l&15, row=(l>>4)*4+reg
    #pragma unroll
    for (int tg = 0; tg < 2; ++tg)
      #pragma unroll
      for (int rr = 0; rr < 4; ++rr)
        gates[(kq * 32 + tg * 16 + gch * 4 + rr) * GATE_STRIDE + cB] = acc[tg][rr];
    __syncthreads();

    // ---- cell update (threads 0..255, one (cb,cu) each)
    if (tid < 256) {
      float s4[4];
      #pragma unroll
      for (int q = 0; q < 4; ++q) {
        int rloc = (q >> 1) * 16 + (q & 1) * 8 + cu;
        float s = bsq[q];
        #pragma unroll
        for (int kp = 0; kp < 4; ++kp)
          s += gates[(kp * 32 + rloc) * GATE_STRIDE + cb];
        s4[q] = s;
      }
      float iv = 1.f / (1.f + __expf(-s4[0]));
      float fv = 1.f / (1.f + __expf(-s4[1]));
      float gv = tanhf(s4[2]);
      float ov = 1.f / (1.f + __expf(-s4[3]));
      c_reg = fv * c_reg + iv * gv;
      float h2 = ov * tanhf(c_reg);
      unsigned short hh = bf_hi(h2);
      unsigned short ll = bf_hi(h2 - bf_val(hh));
      __hip_atomic_store(hdst + (size_t)cb * 512 + hu,
                         (unsigned)hh | ((unsigned)ll << 16),
                         __ATOMIC_RELAXED, __HIP_MEMORY_SCOPE_AGENT);
      if (t == mylen - 1) out[(size_t)gb * HID + hu] = h2;
    }

    __syncthreads();   // drains h stores (vmcnt 0) before flag store
    if (tid == 0)
      __hip_atomic_store(myflags + ug, (unsigned)(t + 1),
                         __ATOMIC_RELAXED, __HIP_MEMORY_SCOPE_AGENT);
  }
}

// ---------------- launch ----------------
extern "C" void kernel_launch(void* const* d_in, const int* in_sizes, int n_in,
                              void* d_out, int out_size, void* d_ws, size_t ws_size,
                              hipStream_t stream)
{
  const float* inputs = (const float*)d_in[0];
  const int*   len    = (const int*)  d_in[1];
  const float* h0     = (const float*)d_in[2];
  const float* c0     = (const float*)d_in[3];
  const float* Wih    = (const float*)d_in[4];
  const float* Whh    = (const float*)d_in[5];
  const float* bih    = (const float*)d_in[6];
  const float* bhh    = (const float*)d_in[7];
  float* out = (float*)d_out;

  char* p = (char*)d_ws;
  unsigned short* xp = (unsigned short*)p; p += (size_t)T_STEPS * 4 * 8192 * 2;      // 64 MB
  unsigned short* wf = (unsigned short*)p; p += (size_t)2560 * 2 * 64 * 8 * 2;       // 5 MB
  unsigned* hp0 = (unsigned*)p;  p += (size_t)4 * 32 * 512 * 4;                      // 256 KB
  unsigned* hp1 = (unsigned*)p;  p += (size_t)4 * 32 * 512 * 4;                      // 256 KB
  unsigned* flags = (unsigned*)p; p += 256 * 4;

  (void)hipFuncSetAttribute((const void*)k_persist,
                            hipFuncAttributeMaxDynamicSharedMemorySize, SMEM_BYTES);

  k_prep_x<<<T_STEPS * 4, 256, 0, stream>>>(inputs, xp);
  k_prep_w<<<2560, 64, 0, stream>>>(Wih, Whh, wf);
  k_prep_h<<<256, 256, 0, stream>>>(h0, hp0, flags);

  void* args[] = {(void*)&xp, (void*)&wf, (void*)&bih, (void*)&bhh,
                  (void*)&hp0, (void*)&hp1, (void*)&c0, (void*)&len,
                  (void*)&out, (void*)&flags};
  (void)hipLaunchCooperativeKernel((void*)k_persist, dim3(NBLK), dim3(NTHR),
                                   args, SMEM_BYTES, stream);
}

// Round 6
// 3054.913 us; speedup vs baseline: 11.5200x; 1.2293x over previous
//
#include <hip/hip_runtime.h>
#include <hip/hip_bf16.h>
#include <cstdint>
#include <cstddef>

#define T_STEPS 1024
#define BATCH   128
#define INF     128   // used input features (130 minus last 2)
#define HID     512
#define NBLK    256   // 32 ug x 8 bg
#define NTHR    512   // 8 waves: kq = w&3 (160-deep k quarter), th = w>>2 (2 of 4 gates)
#define PK      648   // padded k stride (bf16 units) in LDS Z planes
#define Z_SHORTS    (2 * 16 * PK)            // 20736 shorts = 41472 B
#define GSTR        17
#define GATE_FLOATS (4 * 4 * 16 * GSTR)      // 4352 floats = 17408 B
#define SMEM_BYTES  (Z_SHORTS * 2 + GATE_FLOATS * 4)   // 58880 B

typedef short  bf16x8 __attribute__((ext_vector_type(8)));
typedef float  f32x4  __attribute__((ext_vector_type(4)));

static __device__ __forceinline__ unsigned short bf_hi(float v) {
  __hip_bfloat16 h = __float2bfloat16(v);
  return *reinterpret_cast<unsigned short*>(&h);
}
static __device__ __forceinline__ float bf_val(unsigned short u) {
  __hip_bfloat16 h = *reinterpret_cast<__hip_bfloat16*>(&u);
  return __bfloat162float(h);
}
static __device__ __forceinline__ float fsigmoid(float x) {
  return 1.f / (1.f + __expf(-x));
}
static __device__ __forceinline__ float ftanh(float x) {
  return 1.f - 2.f / (__expf(2.f * x) + 1.f);
}

// ---------------- pre-pass kernels ----------------

// xp[t*8+bg][p][c 16][k 128] bf16 (p=0 hi, p=1 lo)
__global__ __launch_bounds__(256) void k_prep_x(const float* __restrict__ in,
                                                unsigned short* __restrict__ xp)
{
  int t = blockIdx.x >> 3, bg = blockIdx.x & 7;
  int tid = threadIdx.x;
  size_t base = (size_t)blockIdx.x * 4096;
  #pragma unroll
  for (int rep = 0; rep < 8; ++rep) {
    int idx = rep * 256 + tid;           // 0..2047
    int c = idx >> 7, k = idx & 127;
    float v = in[((size_t)(bg * 16 + c) * T_STEPS + t) * 130 + k];
    unsigned short hi = bf_hi(v);
    unsigned short lo = bf_hi(v - bf_val(hi));
    xp[base + c * 128 + k]        = hi;
    xp[base + 2048 + c * 128 + k] = lo;
  }
}

// W A-fragments, bf16 hi/lo, per-lane MFMA layout.
// blk = ((ug*4+q)*4+kq)*5+s   (2560 blocks x 64 threads)
// tile q = gate index; rows = 16 units of ug. A lane map: row=l&15, k=(l>>4)*8+j
__global__ __launch_bounds__(64) void k_prep_w(const float* __restrict__ Wih,
                                               const float* __restrict__ Whh,
                                               unsigned short* __restrict__ wf)
{
  int blk = blockIdx.x;
  int s = blk % 5; int r = blk / 5;
  int kq = r & 3; int q = (r >> 2) & 3; int ug = r >> 4;
  int l = threadIdx.x;
  int Grow = q * HID + ug * 16 + (l & 15);
  int kb = kq * 160 + s * 32 + (l >> 4) * 8;
  float v[8];
  #pragma unroll
  for (int j = 0; j < 8; ++j)
    v[j] = (kb < INF) ? Wih[(size_t)Grow * INF + kb + j]
                      : Whh[(size_t)Grow * HID + (kb - INF) + j];
  unsigned short hi[8], lo[8];
  #pragma unroll
  for (int j = 0; j < 8; ++j) {
    hi[j] = bf_hi(v[j]);
    lo[j] = bf_hi(v[j] - bf_val(hi[j]));
  }
  unsigned short* dh = wf + ((size_t)(blk * 2 + 0) * 64 + l) * 8;
  unsigned short* dl = wf + ((size_t)(blk * 2 + 1) * 64 + l) * 8;
  #pragma unroll
  for (int j = 0; j < 8; ++j) { dh[j] = hi[j]; dl[j] = lo[j]; }
}

// hp0[bg][c 16][k 512] u32 = hi | lo<<16 of h0[b][k]; zero flags (256)
__global__ __launch_bounds__(256) void k_prep_h(const float* __restrict__ h0,
                                                unsigned* __restrict__ hp0,
                                                unsigned* __restrict__ flags)
{
  int idx = blockIdx.x * 256 + threadIdx.x;   // 0..65535
  int k = idx & 511, c = (idx >> 9) & 15, bg = idx >> 13;
  float v = h0[(size_t)(bg * 16 + c) * HID + k];
  unsigned short hi = bf_hi(v);
  unsigned short lo = bf_hi(v - bf_val(hi));
  hp0[idx] = (unsigned)hi | ((unsigned)lo << 16);
  if (blockIdx.x == 0 && threadIdx.x < 256) flags[threadIdx.x] = 0;
}

// ---------------- persistent MFMA LSTM ----------------
// 256 blocks = 32 ug (16 units = 64 gate-rows) x 8 bg (16 b). 1 block/CU.
// 8 waves: kq = w&3 (160-deep k quarter), th = w>>2 (gates {2th,2th+1}).
// Per wave: 2 gate-tiles x 5 ksteps x 3 split-MFMAs; 20 named A-frags in regs.
__global__ __launch_bounds__(NTHR, 2) void k_persist(
    const unsigned short* __restrict__ xp,   // [t*8+bg][2][16][128]
    const unsigned short* __restrict__ wf,   // A-fragments
    const float* __restrict__ bih, const float* __restrict__ bhh,
    unsigned* __restrict__ hp0,              // [8][16][512] packed hi|lo<<16
    unsigned* __restrict__ hp1,
    const float* __restrict__ c0,            // [128][512]
    const int* __restrict__ len,
    float* __restrict__ out,                 // [128][512]
    unsigned* __restrict__ flags)            // [8][32]
{
  extern __shared__ char smem[];
  short* zpl   = (short*)smem;                     // [2][16][PK] bf16
  float* gates = (float*)(smem + Z_SHORTS * 2);    // [4 kq][4 q][16 u][GSTR]

  const int blk = blockIdx.x;
  const int ug = blk & 31, bg = blk >> 5;
  const int tid = threadIdx.x;
  const int w = tid >> 6, l = tid & 63;
  const int kq = w & 3, th = w >> 2;
  const int cB = l & 15, gch = l >> 4;
  const int q0 = th * 2, q1 = th * 2 + 1;

  // ---- load 20 W A-fragments into NAMED registers (once)
  const uint4* wfq = (const uint4*)wf;
#define LDW(q_, s_, p_) \
  (*reinterpret_cast<const bf16x8*>(&wfq[(size_t)((((ug * 4 + (q_)) * 4 + kq) * 5 + (s_)) * 2 + (p_)) * 64 + l]))
  bf16x8 Aa0h = LDW(q0,0,0), Aa0l = LDW(q0,0,1), Aa1h = LDW(q0,1,0), Aa1l = LDW(q0,1,1);
  bf16x8 Aa2h = LDW(q0,2,0), Aa2l = LDW(q0,2,1), Aa3h = LDW(q0,3,0), Aa3l = LDW(q0,3,1);
  bf16x8 Aa4h = LDW(q0,4,0), Aa4l = LDW(q0,4,1);
  bf16x8 Ab0h = LDW(q1,0,0), Ab0l = LDW(q1,0,1), Ab1h = LDW(q1,1,0), Ab1l = LDW(q1,1,1);
  bf16x8 Ab2h = LDW(q1,2,0), Ab2l = LDW(q1,2,1), Ab3h = LDW(q1,3,0), Ab3l = LDW(q1,3,1);
  bf16x8 Ab4h = LDW(q1,4,0), Ab4l = LDW(q1,4,1);
#undef LDW
  // keep-alive: forbid the compiler from sinking/rematerializing these loads
  asm volatile("" : "+v"(Aa0h), "+v"(Aa0l), "+v"(Aa1h), "+v"(Aa1l), "+v"(Aa2h),
                    "+v"(Aa2l), "+v"(Aa3h), "+v"(Aa3l), "+v"(Aa4h), "+v"(Aa4l),
                    "+v"(Ab0h), "+v"(Ab0l), "+v"(Ab1h), "+v"(Ab1l), "+v"(Ab2h),
                    "+v"(Ab2l), "+v"(Ab3h), "+v"(Ab3l), "+v"(Ab4h), "+v"(Ab4l));

  // ---- per-cell state (threads 0..255: cell (cb, cu))
  const int cb = tid & 15, cu = (tid >> 4) & 15;
  const int gb = bg * 16 + cb, hu = ug * 16 + cu;
  float c_reg = 0.f, bsq[4] = {0.f, 0.f, 0.f, 0.f};
  int mylen = -1;
  if (tid < 256) {
    c_reg = c0[(size_t)gb * HID + hu];
    mylen = len[gb];
    #pragma unroll
    for (int q = 0; q < 4; ++q) bsq[q] = bih[q * HID + hu] + bhh[q * HID + hu];
  }

  unsigned* myflags = flags + bg * 32;

  for (int t = 0; t < T_STEPS; ++t) {
    // ---- x stage (h-independent): 8KB straight copy into LDS planes (k<128)
    {
      const uint4* xps = (const uint4*)(xp + (size_t)(t * 8 + bg) * 4096);
      uint4 xa = xps[tid];
      int p = tid >> 8, c = (tid >> 4) & 15, kc = tid & 15;
      *(uint4*)(zpl + (p * 16 + c) * PK + kc * 8) = xa;
    }

    // ---- wait for the 32 peer blocks of this bg to finish step t-1
    if (t) {
      if (tid < 32) {
        while (__hip_atomic_load(myflags + tid, __ATOMIC_RELAXED,
                                 __HIP_MEMORY_SCOPE_AGENT) < (unsigned)t)
          __builtin_amdgcn_s_sleep(1);
      }
      __syncthreads();
    }
    const unsigned* hsrc = ((t & 1) ? hp1 : hp0) + (size_t)bg * 8192;
    unsigned*       hdst = ((t & 1) ? hp0 : hp1) + (size_t)bg * 8192;

    // ---- h load (far point) + stage into planes (k>=128)
    unsigned long long hch[8];
    const unsigned long long* hq = (const unsigned long long*)hsrc;
    #pragma unroll
    for (int j = 0; j < 8; ++j)
      hch[j] = __hip_atomic_load(hq + j * 512 + tid, __ATOMIC_RELAXED,
                                 __HIP_MEMORY_SCOPE_AGENT);
    #pragma unroll
    for (int j = 0; j < 8; ++j) {
      int ci = j * 512 + tid;
      int c = ci >> 8, kp = ci & 255;
      unsigned w0 = (unsigned)hch[j], w1 = (unsigned)(hch[j] >> 32);
      unsigned hipair = (w0 & 0xFFFFu) | (w1 << 16);
      unsigned lopair = (w0 >> 16) | (w1 & 0xFFFF0000u);
      *(unsigned*)(zpl + c * PK + 128 + 2 * kp)        = hipair;
      *(unsigned*)(zpl + (16 + c) * PK + 128 + 2 * kp) = lopair;
    }
    __syncthreads();

    // ---- MFMA phase: 2 gate-tiles x 5 ksteps x 3 split products
    f32x4 acc0 = {0, 0, 0, 0}, acc1 = {0, 0, 0, 0};
#define KSTEP(s_, AH0, AL0, AH1, AL1)                                          \
  {                                                                            \
    int ka = kq * 160 + (s_) * 32 + gch * 8;                                   \
    bf16x8 Bh = *(const bf16x8*)(zpl + cB * PK + ka);                          \
    bf16x8 Bl = *(const bf16x8*)(zpl + (16 + cB) * PK + ka);                   \
    acc0 = __builtin_amdgcn_mfma_f32_16x16x32_bf16(AH0, Bh, acc0, 0, 0, 0);    \
    acc0 = __builtin_amdgcn_mfma_f32_16x16x32_bf16(AH0, Bl, acc0, 0, 0, 0);    \
    acc0 = __builtin_amdgcn_mfma_f32_16x16x32_bf16(AL0, Bh, acc0, 0, 0, 0);    \
    acc1 = __builtin_amdgcn_mfma_f32_16x16x32_bf16(AH1, Bh, acc1, 0, 0, 0);    \
    acc1 = __builtin_amdgcn_mfma_f32_16x16x32_bf16(AH1, Bl, acc1, 0, 0, 0);    \
    acc1 = __builtin_amdgcn_mfma_f32_16x16x32_bf16(AL1, Bh, acc1, 0, 0, 0);    \
  }
    KSTEP(0, Aa0h, Aa0l, Ab0h, Ab0l)
    KSTEP(1, Aa1h, Aa1l, Ab1h, Ab1l)
    KSTEP(2, Aa2h, Aa2l, Ab2h, Ab2l)
    KSTEP(3, Aa3h, Aa3l, Ab3h, Ab3l)
    KSTEP(4, Aa4h, Aa4l, Ab4h, Ab4l)
#undef KSTEP

    // ---- dump partial gates: C layout col=l&15, row(unit)=(l>>4)*4+reg
    #pragma unroll
    for (int rr = 0; rr < 4; ++rr) {
      gates[((kq * 4 + q0) * 16 + gch * 4 + rr) * GSTR + cB] = acc0[rr];
      gates[((kq * 4 + q1) * 16 + gch * 4 + rr) * GSTR + cB] = acc1[rr];
    }
    __syncthreads();

    // ---- cell update (threads 0..255, one (cb,cu) each)
    if (tid < 256) {
      float s4[4];
      #pragma unroll
      for (int q = 0; q < 4; ++q) {
        float s = bsq[q];
        #pragma unroll
        for (int kp = 0; kp < 4; ++kp)
          s += gates[((kp * 4 + q) * 16 + cu) * GSTR + cb];
        s4[q] = s;
      }
      float iv = fsigmoid(s4[0]);
      float fv = fsigmoid(s4[1]);
      float gv = ftanh(s4[2]);
      float ov = fsigmoid(s4[3]);
      c_reg = fv * c_reg + iv * gv;
      float h2 = ov * ftanh(c_reg);
      unsigned short hh = bf_hi(h2);
      unsigned short ll = bf_hi(h2 - bf_val(hh));
      __hip_atomic_store(hdst + (size_t)cb * 512 + hu,
                         (unsigned)hh | ((unsigned)ll << 16),
                         __ATOMIC_RELAXED, __HIP_MEMORY_SCOPE_AGENT);
      if (t == mylen - 1) out[(size_t)gb * HID + hu] = h2;
    }

    __syncthreads();   // drains h stores (vmcnt 0) before flag store
    if (tid == 0)
      __hip_atomic_store(myflags + ug, (unsigned)(t + 1),
                         __ATOMIC_RELAXED, __HIP_MEMORY_SCOPE_AGENT);
  }
}

// ---------------- launch ----------------
extern "C" void kernel_launch(void* const* d_in, const int* in_sizes, int n_in,
                              void* d_out, int out_size, void* d_ws, size_t ws_size,
                              hipStream_t stream)
{
  const float* inputs = (const float*)d_in[0];
  const int*   len    = (const int*)  d_in[1];
  const float* h0     = (const float*)d_in[2];
  const float* c0     = (const float*)d_in[3];
  const float* Wih    = (const float*)d_in[4];
  const float* Whh    = (const float*)d_in[5];
  const float* bih    = (const float*)d_in[6];
  const float* bhh    = (const float*)d_in[7];
  float* out = (float*)d_out;

  char* p = (char*)d_ws;
  unsigned short* xp = (unsigned short*)p; p += (size_t)T_STEPS * 8 * 4096 * 2;      // 64 MB
  unsigned short* wf = (unsigned short*)p; p += (size_t)2560 * 2 * 64 * 8 * 2;       // 5 MB
  unsigned* hp0 = (unsigned*)p;  p += (size_t)8 * 16 * 512 * 4;                      // 256 KB
  unsigned* hp1 = (unsigned*)p;  p += (size_t)8 * 16 * 512 * 4;                      // 256 KB
  unsigned* flags = (unsigned*)p; p += 256 * 4;

  (void)hipFuncSetAttribute((const void*)k_persist,
                            hipFuncAttributeMaxDynamicSharedMemorySize, SMEM_BYTES);

  k_prep_x<<<T_STEPS * 8, 256, 0, stream>>>(inputs, xp);
  k_prep_w<<<2560, 64, 0, stream>>>(Wih, Whh, wf);
  k_prep_h<<<256, 256, 0, stream>>>(h0, hp0, flags);

  void* args[] = {(void*)&xp, (void*)&wf, (void*)&bih, (void*)&bhh,
                  (void*)&hp0, (void*)&hp1, (void*)&c0, (void*)&len,
                  (void*)&out, (void*)&flags};
  (void)hipLaunchCooperativeKernel((void*)k_persist, dim3(NBLK), dim3(NTHR),
                                   args, SMEM_BYTES, stream);
}